// Round 3
// baseline (131.540 us; speedup 1.0000x reference)
//
#include <hip/hip_runtime.h>

// MaskToken: B=4, L=4096, D=1024, NUM_KEEP=1024 (sorted idx_keep), NUM_DROP=3072.
// Outputs (concat, float32 view):
//   out0 = outputs_dropped  [B, NUM_KEEP, D]   = gather of kept rows
//   out1 = outputs_masked   [B, L, D]          = kept rows passthrough, dropped rows = mask_embedding
//   out2 = mask_drop        [L]                = 1.0 where dropped else 0.0
//   out3 = idx_keep         [NUM_KEEP]         = written as float values
//
// Round-2 restructure: amortize per-block overhead (dispatch, idx/me loads,
// barriers) over 8 rows per block. Grid = 2048 blocks = exactly 8 blocks/CU
// x 256 CU (one full residency round, 32 waves/CU, LDS 16KB -> still 8/CU).
// Per block: build LDS inverse-rank table rank[l] once (init -1 + scatter of
// the 1024 keep ranks, 2 barriers), then each row is ONE broadcast LDS read
// (uniform address, conflict-free) + the streaming float4 work. Row
// iterations are independent -> ILP across rows. Targets the ~7us gap
// between the observed ~23us kernel and its ~15.5us memory floor
// (100.7 MB @ ~6.5 TB/s), attributed to 16384-block dispatch + per-row
// table/barrier overhead.

#define B_ 4
#define L_ 4096
#define D_ 1024
#define NKEEP_ 1024
#define ROWS_PER_BLOCK 8

__global__ __launch_bounds__(256) void masktoken_kernel(
    const float4* __restrict__ in,        // [B*L*D/4]
    const float4* __restrict__ me,        // [D/4] mask embedding
    const int4*   __restrict__ idx_keep4, // [NKEEP_/4] sorted
    float4* __restrict__ out0,            // [B*NKEEP_*D/4]
    float4* __restrict__ out1,            // [B*L*D/4]
    float*  __restrict__ out2,            // [L]
    float*  __restrict__ out3)            // [NKEEP_]
{
    const int t = threadIdx.x;            // 0..255

    __shared__ int srank[L_];             // 16KB: rank[l] or -1

    // Hoisted loads: keep-table quad + mask-embedding quad (reused all rows).
    const int4   kv = idx_keep4[t];
    const float4 mv = me[t];

    // Build inverse-rank table: init -1, scatter ranks. 2 barriers per BLOCK
    // (was 2 per ROW).
    #pragma unroll
    for (int i = 0; i < L_ / 256; ++i) srank[t + 256 * i] = -1;
    __syncthreads();
    srank[kv.x] = 4 * t + 0;
    srank[kv.y] = 4 * t + 1;
    srank[kv.z] = 4 * t + 2;
    srank[kv.w] = 4 * t + 3;
    __syncthreads();

    const int row0 = blockIdx.x * ROWS_PER_BLOCK;

    #pragma unroll
    for (int i = 0; i < ROWS_PER_BLOCK; ++i) {
        const int row = row0 + i;
        const int b   = row >> 12;        // row / L
        const int l   = row & (L_ - 1);   // row % L

        const int r = srank[l];           // uniform-address LDS read: broadcast

        const size_t rowOff = (size_t)row * (D_ / 4);
        if (r >= 0) {                     // wave-uniform branch (no divergence)
            float4 v = in[rowOff + t];
            out1[rowOff + t] = v;                                      // passthrough
            out0[((size_t)b * NKEEP_ + (size_t)r) * (D_ / 4) + t] = v; // gather
        } else {
            out1[rowOff + t] = mv;                                     // mask embedding
        }

        if (b == 0 && t == 0) {
            out2[l] = (r < 0) ? 1.0f : 0.0f;
            if (r >= 0) out3[r] = (float)l;   // idx_keep[r] == l by construction
        }
    }
}

extern "C" void kernel_launch(void* const* d_in, const int* in_sizes, int n_in,
                              void* d_out, int out_size, void* d_ws, size_t ws_size,
                              hipStream_t stream) {
    const float4* in  = (const float4*)d_in[0];       // inputs [B,L,D]
    const float4* me  = (const float4*)d_in[1];       // mask_embedding [D]
    const int4*   idx = (const int4*)d_in[2];         // idx_keep [NKEEP_]

    float* out = (float*)d_out;
    float4* out0 = (float4*)out;                                  // B*NKEEP_*D
    float4* out1 = (float4*)(out + (size_t)B_ * NKEEP_ * D_);     // B*L*D
    float*  out2 = out + (size_t)B_ * NKEEP_ * D_ + (size_t)B_ * L_ * D_;  // L
    float*  out3 = out2 + L_;                                     // NKEEP_

    dim3 grid(B_ * L_ / ROWS_PER_BLOCK);  // 2048
    dim3 block(256);
    masktoken_kernel<<<grid, block, 0, stream>>>(in, me, idx, out0, out1, out2, out3);
}

// Round 5
// 128.144 us; speedup vs baseline: 1.0265x; 1.0265x over previous
//
#include <hip/hip_runtime.h>

// MaskToken: B=4, L=4096, D=1024, NUM_KEEP=1024 (sorted idx_keep), NUM_DROP=3072.
// Outputs (concat, float32 view):
//   out0 = outputs_dropped  [B, NUM_KEEP, D]   = gather of kept rows
//   out1 = outputs_masked   [B, L, D]          = kept passthrough, dropped = mask_embedding
//   out2 = mask_drop        [L]
//   out3 = idx_keep         [NUM_KEEP] (as float)
//
// R4 design notes (post-mortems R2/R3):
//  - R3 (2048 blocks = EXACTLY one residency round, 8 consecutive rows/block)
//    regressed ~23->30us: zero dynamic rebalancing + 3:1 data-dependent
//    per-block work => slowest CU sets the time. Keep many small blocks.
//  - This version: 8192 blocks; each owns one l and TWO batches (b-pair).
//    Probe amortized 2x, dispatches halved, per-block work still small
//    (kept 24KB / dropped 8KB) with 4 residency rounds of rebalancing.
//  - Probe is BARRIER-FREE: each wave reads the whole 1024-entry sorted
//    idx_keep (16 entries/lane, 4 coalesced L1-hot int4 loads), then
//    __ballot + one __shfl publishes the rank. No LDS, no __syncthreads
//    (R2 paid 2 barriers x 4-wave sync per row).

#define B_ 4
#define L_ 4096
#define D_ 1024
#define NKEEP_ 1024

__global__ __launch_bounds__(256) void masktoken_kernel(
    const float4* __restrict__ in,        // [B*L*D/4]
    const float4* __restrict__ me,        // [D/4] mask embedding
    const int4*   __restrict__ idx_keep4, // [NKEEP_/4] sorted
    float4* __restrict__ out0,            // [B*NKEEP_*D/4]
    float4* __restrict__ out1,            // [B*L*D/4]
    float*  __restrict__ out2,            // [L]
    float*  __restrict__ out3)            // [NKEEP_]
{
    const int q    = blockIdx.x;          // 0..8191
    const int l    = q & (L_ - 1);        // row index within sequence
    const int bp   = q >> 12;             // b-pair: 0 -> b{0,1}, 1 -> b{2,3}
    const int t    = threadIdx.x;         // 0..255 -> float4 slot in row
    const int lane = t & 63;

    // Hoist mask-embedding quad so its L1 latency overlaps the probe.
    const float4 mv = me[t];

    // Wave-parallel probe of the full table: lane covers entries
    // 4*(lane+64j)+c for j=0..3. At most one lane in the wave matches.
    int m = -1;
    #pragma unroll
    for (int j = 0; j < 4; ++j) {
        const int  k4 = lane + 64 * j;
        const int4 kv = idx_keep4[k4];
        const int  kb = 4 * k4;
        if (kv.x == l) m = kb + 0;
        if (kv.y == l) m = kb + 1;
        if (kv.z == l) m = kb + 2;
        if (kv.w == l) m = kb + 3;
    }
    const unsigned long long bal = __ballot(m >= 0);
    const int r = bal ? __shfl(m, __ffsll((long long)bal) - 1) : -1;

    const int b0 = bp << 1;
    #pragma unroll
    for (int bb = 0; bb < 2; ++bb) {
        const int b = b0 + bb;
        const size_t rowOff = (size_t)(b * L_ + l) * (D_ / 4);
        if (r >= 0) {                     // wave-uniform branch
            float4 v = in[rowOff + t];
            out1[rowOff + t] = v;                                      // passthrough
            out0[((size_t)b * NKEEP_ + (size_t)r) * (D_ / 4) + t] = v; // gather
        } else {
            out1[rowOff + t] = mv;                                     // mask embedding
        }
    }

    if (bp == 0 && t == 0) {
        out2[l] = (r < 0) ? 1.0f : 0.0f;
        if (r >= 0) out3[r] = (float)l;   // idx_keep[r] == l by construction
    }
}

extern "C" void kernel_launch(void* const* d_in, const int* in_sizes, int n_in,
                              void* d_out, int out_size, void* d_ws, size_t ws_size,
                              hipStream_t stream) {
    const float4* in  = (const float4*)d_in[0];       // inputs [B,L,D]
    const float4* me  = (const float4*)d_in[1];       // mask_embedding [D]
    const int4*   idx = (const int4*)d_in[2];         // idx_keep [NKEEP_]

    float* out = (float*)d_out;
    float4* out0 = (float4*)out;                                  // B*NKEEP_*D
    float4* out1 = (float4*)(out + (size_t)B_ * NKEEP_ * D_);     // B*L*D
    float*  out2 = out + (size_t)B_ * NKEEP_ * D_ + (size_t)B_ * L_ * D_;  // L
    float*  out3 = out2 + L_;                                     // NKEEP_

    dim3 grid(2 * L_);                    // 8192 blocks: (b-pair, l)
    dim3 block(256);
    masktoken_kernel<<<grid, block, 0, stream>>>(in, me, idx, out0, out1, out2, out3);
}

// Round 7
// 127.915 us; speedup vs baseline: 1.0283x; 1.0018x over previous
//
#include <hip/hip_runtime.h>

// MaskToken: B=4, L=4096, D=1024, NUM_KEEP=1024 (sorted idx_keep), NUM_DROP=3072.
// Outputs (concat, float32 view):
//   out0 = outputs_dropped  [B, NUM_KEEP, D]   = gather of kept rows
//   out1 = outputs_masked   [B, L, D]          = kept rows passthrough, dropped rows = mask_embedding
//   out2 = mask_drop        [L]                = 1.0 where dropped else 0.0
//   out3 = idx_keep         [NUM_KEEP]         = written as float values
//
// FINAL (revert to best-measured R2 design, 125.6us):
//  - One block per (b,l) row, 16384 blocks: grid order == memory order
//    (sequential HBM streaming; R5's b-pair blocks touching streams 16MB
//    apart regressed 23->28us) and fine-grained dynamic load balance
//    (R3's 2048-block one-residency-round design regressed 23->30us).
//  - Rank lookup: all 256 threads probe the 1024-entry sorted idx_keep in
//    ONE int4 L1-resident load each; unique matching thread broadcasts its
//    rank via a 4B LDS slot (replaces the original 10-step dependent
//    binary search, 129.4 -> 125.6us).
//  - Kernel ~23us vs ~15.5us pure-traffic floor (100.7 MB @ 6.7 TB/s);
//    gap = mixed R/W turnaround + launch overhead. Remaining timed region
//    is ~100us of harness poison fills already at 83-84% HBM peak.

#define B_ 4
#define L_ 4096
#define D_ 1024
#define NKEEP_ 1024

__global__ __launch_bounds__(256) void masktoken_kernel(
    const float4* __restrict__ in,        // [B*L*D/4]
    const float4* __restrict__ me,        // [D/4] mask embedding
    const int4*   __restrict__ idx_keep4, // [NKEEP_/4] sorted
    float4* __restrict__ out0,            // [B*NKEEP_*D/4]
    float4* __restrict__ out1,            // [B*L*D/4]
    float*  __restrict__ out2,            // [L]
    float*  __restrict__ out3)            // [NKEEP_]
{
    const int row = blockIdx.x;           // 0 .. B*L-1
    const int b   = row >> 12;            // row / L
    const int l   = row & (L_ - 1);       // row % L
    const int t   = threadIdx.x;          // 0..255 -> float4 slot in row

    __shared__ int sr;

    // Issue both independent L1-resident loads immediately so their latency
    // overlaps the barrier/compare sequence below.
    const int4   kv = idx_keep4[t];       // ranks 4t..4t+3 of the keep table
    const float4 mv = me[t];              // mask-embedding quad for this slot

    if (t == 0) sr = -1;
    __syncthreads();

    int m = -1;
    if (kv.x == l) m = 4 * t + 0;
    if (kv.y == l) m = 4 * t + 1;
    if (kv.z == l) m = 4 * t + 2;
    if (kv.w == l) m = 4 * t + 3;
    if (m >= 0) sr = m;                   // at most one thread matches
    __syncthreads();

    const int r = sr;                     // rank in idx_keep, or -1 if dropped

    const size_t rowOff = (size_t)row * (D_ / 4);
    if (r >= 0) {
        float4 v = in[rowOff + t];
        out1[rowOff + t] = v;                                      // passthrough
        out0[((size_t)b * NKEEP_ + (size_t)r) * (D_ / 4) + t] = v; // gather
    } else {
        out1[rowOff + t] = mv;                                     // mask embedding
    }

    if (b == 0 && t == 0) {
        out2[l] = (r < 0) ? 1.0f : 0.0f;
        if (r >= 0) out3[r] = (float)l;   // idx_keep[r] == l by construction
    }
}

extern "C" void kernel_launch(void* const* d_in, const int* in_sizes, int n_in,
                              void* d_out, int out_size, void* d_ws, size_t ws_size,
                              hipStream_t stream) {
    const float4* in  = (const float4*)d_in[0];       // inputs [B,L,D]
    const float4* me  = (const float4*)d_in[1];       // mask_embedding [D]
    const int*    idx_raw = (const int*)d_in[2];      // idx_keep [NKEEP_]
    const int4*   idx = (const int4*)idx_raw;

    float* out = (float*)d_out;
    float4* out0 = (float4*)out;                                  // B*NKEEP_*D
    float4* out1 = (float4*)(out + (size_t)B_ * NKEEP_ * D_);     // B*L*D
    float*  out2 = out + (size_t)B_ * NKEEP_ * D_ + (size_t)B_ * L_ * D_;  // L
    float*  out3 = out2 + L_;                                     // NKEEP_

    dim3 grid(B_ * L_);
    dim3 block(256);
    masktoken_kernel<<<grid, block, 0, stream>>>(in, me, idx, out0, out1, out2, out3);
}